// Round 2
// 223.745 us; speedup vs baseline: 1.0068x; 1.0068x over previous
//
#include <hip/hip_runtime.h>
#include <math.h>

#define D        2048
#define E        64
#define NROWS    16384              // B*S = 4*4096

// ---------------- fused MFMA path geometry ----------------
#define ROWS_PB  32                 // rows per block
#define BKC      64                 // K per chunk
#define NCH      (D / BKC)          // 32 chunks
#define LDX      72                 // LDS row stride (fp16 elems) for x tiles
#define LDW      72                 // LDS row stride (fp16 elems) for W tiles
// per-buffer LDS layout (in shorts):
//   xh[32*72]=2304 | xl 2304 | wh[64*72]=4608 | wl 4608  => 13824 shorts
#define BUF_SHORTS 13824
#define WCVT_BYTES ((size_t)2 * E * D * sizeof(unsigned short))   // 512 KB

// lo-term scaling: lo' = (v - fp16(v)) * 2^11  (keeps lo in fp16 NORMAL range;
// avoids any MFMA denormal-flush hazard). Recombine with 2^-11 / 2^-22.
#define LSCALE   2048.0f
#define S1       4.8828125e-4f            // 2^-11
#define S2       2.384185791015625e-7f    // 2^-22

typedef __attribute__((ext_vector_type(8))) _Float16 f16x8;
typedef __attribute__((ext_vector_type(4))) float f32x4;

__device__ __forceinline__ unsigned short f2h(float f) {
    union { _Float16 h; unsigned short u; } c;
    c.h = (_Float16)f;                 // v_cvt_f16_f32, RNE
    return c.u;
}
__device__ __forceinline__ float h2f(unsigned short u) {
    union { _Float16 h; unsigned short u; } c;
    c.u = u;
    return (float)c.h;
}

// ============ K0: split W (fp32) -> W_hi, W_lo' (fp16, RNE) =================
// 64 blocks x 256 thr x 8 elems = 131072 = 64*2048. Runs every launch (ws is
// re-poisoned by the harness).
__global__ __launch_bounds__(256)
void w_cvt(const float* __restrict__ W,
           unsigned short* __restrict__ whi,
           unsigned short* __restrict__ wlo)
{
    const int i = (blockIdx.x * 256 + threadIdx.x) << 3;
    const float4 a = *(const float4*)(W + i);
    const float4 b = *(const float4*)(W + i + 4);
    float vv[8] = {a.x, a.y, a.z, a.w, b.x, b.y, b.z, b.w};
    unsigned int hw[4], lw[4];
#pragma unroll
    for (int j = 0; j < 4; ++j) {
        const unsigned short h0 = f2h(vv[2*j]);
        const unsigned short h1 = f2h(vv[2*j+1]);
        const unsigned short l0 = f2h((vv[2*j]   - h2f(h0)) * LSCALE);
        const unsigned short l1 = f2h((vv[2*j+1] - h2f(h1)) * LSCALE);
        hw[j] = (unsigned int)h0 | ((unsigned int)h1 << 16);
        lw[j] = (unsigned int)l0 | ((unsigned int)l1 << 16);
    }
    *(uint4*)(whi + i) = make_uint4(hw[0], hw[1], hw[2], hw[3]);
    *(uint4*)(wlo + i) = make_uint4(lw[0], lw[1], lw[2], lw[3]);
}

// ============ K1: fused fp16x4-split MFMA GEMM + softmax + top2 =============
// Grid 512 x 256 thr (4 waves). Block tile: 32 rows x 64 experts x full K.
// Wave w owns rows [(w>>1)*16,+16) x cols [(w&1)*32,+32).
// x*(1+0.1*s) split to fp16 hi/lo' at staging; W pre-split in ws.
// Per output tile, 3 accumulators by scale class: hh (x1), hl+lh (x2^-11),
// ll (x2^-22) -> ~fp32 logits (err ~1e-6 abs; top-2 order matches fp32 ref).
// LDS stride 72 fp16 (144 B): conflict-free ds ops. Double buffer, single
// barrier per chunk.
__global__ __launch_bounds__(256)
void moe_fused(const float* __restrict__ x,
               const unsigned short* __restrict__ whi,
               const unsigned short* __restrict__ wlo,
               const float* __restrict__ scond,
               const int* __restrict__ sidx,
               const float* __restrict__ noise,
               float* __restrict__ dispatch,
               float* __restrict__ probs,
               float* __restrict__ sel)
{
    __shared__ unsigned short smem[2 * BUF_SHORTS];   // 55296 B

    const int t = threadIdx.x;
    const int l = t & 63;
    const int w = t >> 6;

    const float factor = 1.0f + 0.1f * scond[sidx[0]];

    // staging maps
    const int xrow = t >> 3;            // 0..31
    const int xoct = t & 7;             // k octet (8 floats each)
    const int we_  = t >> 2;            // 0..63 expert
    const int wko  = (t & 3) << 4;      // 0,16,32,48 (k offset, elems)

    // wave / fragment maps
    const int R  = (w >> 1) << 4;       // wave row base: 0 / 16
    const int CB = (w & 1) << 5;        // wave col base: 0 / 32
    const int fr = l & 15;
    const int fq = l >> 4;

    const int rowG0 = blockIdx.x * ROWS_PB;

    const float* xg = x + (size_t)(rowG0 + xrow) * D + (xoct << 3);
    const unsigned short* wgh = whi + (size_t)we_ * D + wko;
    const unsigned short* wgl = wlo + (size_t)we_ * D + wko;

    f32x4 acc0h = {0.f,0.f,0.f,0.f}, acc0m = {0.f,0.f,0.f,0.f}, acc0l = {0.f,0.f,0.f,0.f};
    f32x4 acc1h = {0.f,0.f,0.f,0.f}, acc1m = {0.f,0.f,0.f,0.f}, acc1l = {0.f,0.f,0.f,0.f};

    // prefetch chunk 0
    float4 xa = *(const float4*)(xg);
    float4 xb = *(const float4*)(xg + 4);
    uint4  wa = *(const uint4*)(wgh);
    uint4  wb = *(const uint4*)(wgh + 8);
    uint4  wc = *(const uint4*)(wgl);
    uint4  wd = *(const uint4*)(wgl + 8);

    for (int c = 0; c < NCH; ++c) {
        unsigned short* base = smem + (c & 1) * BUF_SHORTS;
        unsigned short* xh = base;
        unsigned short* xl = base + 2304;
        unsigned short* wh = base + 4608;
        unsigned short* wl = base + 9216;

        // ---- stage x: scale, split to fp16 hi/lo', pack, 2x b128 writes ----
        {
            float vv[8] = {xa.x * factor, xa.y * factor, xa.z * factor, xa.w * factor,
                           xb.x * factor, xb.y * factor, xb.z * factor, xb.w * factor};
            unsigned int xhw[4], xlw[4];
#pragma unroll
            for (int j = 0; j < 4; ++j) {
                const unsigned short h0 = f2h(vv[2*j]);
                const unsigned short h1 = f2h(vv[2*j+1]);
                const unsigned short l0 = f2h((vv[2*j]   - h2f(h0)) * LSCALE);
                const unsigned short l1 = f2h((vv[2*j+1] - h2f(h1)) * LSCALE);
                xhw[j] = (unsigned int)h0 | ((unsigned int)h1 << 16);
                xlw[j] = (unsigned int)l0 | ((unsigned int)l1 << 16);
            }
            const int o = xrow * LDX + (xoct << 3);
            *(uint4*)&xh[o] = make_uint4(xhw[0], xhw[1], xhw[2], xhw[3]);
            *(uint4*)&xl[o] = make_uint4(xlw[0], xlw[1], xlw[2], xlw[3]);
        }
        // ---- stage W (already fp16): 4x b128 writes ----
        {
            const int o = we_ * LDW + wko;
            *(uint4*)&wh[o]     = wa;
            *(uint4*)&wh[o + 8] = wb;
            *(uint4*)&wl[o]     = wc;
            *(uint4*)&wl[o + 8] = wd;
        }

        __syncthreads();

        // prefetch chunk c+1 (in flight across the MFMA block)
        if (c + 1 < NCH) {
            const int k0 = (c + 1) << 6;
            xa = *(const float4*)(xg + k0);
            xb = *(const float4*)(xg + k0 + 4);
            wa = *(const uint4*)(wgh + k0);
            wb = *(const uint4*)(wgh + k0 + 8);
            wc = *(const uint4*)(wgl + k0);
            wd = *(const uint4*)(wgl + k0 + 8);
        }

        // ---- MFMA: 2 k-steps x (6 ds_read_b128 + 8 mfma) ----
#pragma unroll
        for (int ks = 0; ks < 2; ++ks) {
            const int ko = (ks << 5) + (fq << 3);
            const f16x8 ah  = *(const f16x8*)&xh[(R + fr) * LDX + ko];
            const f16x8 al  = *(const f16x8*)&xl[(R + fr) * LDX + ko];
            const f16x8 b0h = *(const f16x8*)&wh[(CB + fr) * LDW + ko];
            const f16x8 b0l = *(const f16x8*)&wl[(CB + fr) * LDW + ko];
            const f16x8 b1h = *(const f16x8*)&wh[(CB + 16 + fr) * LDW + ko];
            const f16x8 b1l = *(const f16x8*)&wl[(CB + 16 + fr) * LDW + ko];
            acc0h = __builtin_amdgcn_mfma_f32_16x16x32_f16(ah, b0h, acc0h, 0, 0, 0);
            acc0m = __builtin_amdgcn_mfma_f32_16x16x32_f16(ah, b0l, acc0m, 0, 0, 0);
            acc0m = __builtin_amdgcn_mfma_f32_16x16x32_f16(al, b0h, acc0m, 0, 0, 0);
            acc0l = __builtin_amdgcn_mfma_f32_16x16x32_f16(al, b0l, acc0l, 0, 0, 0);
            acc1h = __builtin_amdgcn_mfma_f32_16x16x32_f16(ah, b1h, acc1h, 0, 0, 0);
            acc1m = __builtin_amdgcn_mfma_f32_16x16x32_f16(ah, b1l, acc1m, 0, 0, 0);
            acc1m = __builtin_amdgcn_mfma_f32_16x16x32_f16(al, b1h, acc1m, 0, 0, 0);
            acc1l = __builtin_amdgcn_mfma_f32_16x16x32_f16(al, b1l, acc1l, 0, 0, 0);
        }
    }

    // ---- epilogue: logits -> LDS [32][68] f32, then per-wave 8 rows ----
    __syncthreads();                       // buffers dead; alias as float
    float* lg = (float*)smem;
#pragma unroll
    for (int j = 0; j < 4; ++j) {
        const int rr = R + (fq << 2) + j;
        lg[rr * 68 + CB + fr]      = acc0h[j] + S1 * acc0m[j] + S2 * acc0l[j];
        lg[rr * 68 + CB + 16 + fr] = acc1h[j] + S1 * acc1m[j] + S2 * acc1l[j];
    }
    __syncthreads();

    const int r0 = w << 3;                 // 8 rows per wave
    float nz[8];
#pragma unroll
    for (int i = 0; i < 8; ++i)
        nz[i] = noise[(size_t)(rowG0 + r0 + i) * E + l];

#pragma unroll 2
    for (int i = 0; i < 8; ++i) {
        const int G = rowG0 + r0 + i;
        const float v = lg[(r0 + i) * 68 + l] + 0.1f * nz[i];

        float m = v;
#pragma unroll
        for (int off = 32; off > 0; off >>= 1)
            m = fmaxf(m, __shfl_xor(m, off, 64));
        const float p = expf(v - m);
        float s = p;
#pragma unroll
        for (int off = 32; off > 0; off >>= 1)
            s += __shfl_xor(s, off, 64);
        const float prob = p / s;
        probs[(size_t)G * E + l] = prob;

        float bv = prob; int bi = l;
#pragma unroll
        for (int off = 32; off > 0; off >>= 1) {
            const float ov = __shfl_xor(bv, off, 64);
            const int   oi = __shfl_xor(bi, off, 64);
            if (ov > bv || (ov == bv && oi < bi)) { bv = ov; bi = oi; }
        }
        float cv = (l == bi) ? -INFINITY : prob;
        int ci = l;
#pragma unroll
        for (int off = 32; off > 0; off >>= 1) {
            const float ov = __shfl_xor(cv, off, 64);
            const int   oi = __shfl_xor(ci, off, 64);
            if (ov > cv || (ov == cv && oi < ci)) { cv = ov; ci = oi; }
        }

        const float sum2 = bv + cv;
        float dval = 0.f;
        if (l == bi) dval = bv / sum2;
        if (l == ci) dval = cv / sum2;
        dispatch[(size_t)G * E + l] = dval;

        if (l == 0) {
            float2 sv; sv.x = (float)bi; sv.y = (float)ci;
            *(float2*)(sel + (size_t)G * 2) = sv;
        }
    }
}

// ================== Fallback pair (round-2, known-good) =====================
__global__ __launch_bounds__(256)
void gemm_r2(const float* __restrict__ x, const float* __restrict__ W,
             const float* __restrict__ scond, const float* __restrict__ noise,
             const int* __restrict__ sidx, float* __restrict__ logits_out)
{
    __shared__ float4 xsb[32][17];
    __shared__ float4 wsh[64][16];
    const int tid = threadIdx.x;
    const int rowBase = blockIdx.x * 32;
    const float factor = 1.0f + 0.1f * scond[sidx[0]];
    const int xk = tid & 15, xr = tid >> 4, we = tid & 63, wk = tid >> 6;
    const int eg = tid & 15, rg = tid >> 4, e0 = eg << 2;
    float acc[2][4];
#pragma unroll
    for (int i = 0; i < 2; ++i)
#pragma unroll
        for (int j = 0; j < 4; ++j) acc[i][j] = 0.f;
    const float* xg = x + (size_t)rowBase * D;
    float4 xb[2], wb[4];
#pragma unroll
    for (int i = 0; i < 2; ++i)
        xb[i] = *(const float4*)(xg + (xr + 16 * i) * D + (xk << 2));
#pragma unroll
    for (int j = 0; j < 4; ++j)
        wb[j] = *(const float4*)(W + we * D + (wk << 4) + (j << 2));
    for (int t = 0; t < 32; ++t) {
#pragma unroll
        for (int i = 0; i < 2; ++i) {
            float4 v = xb[i];
            v.x *= factor; v.y *= factor; v.z *= factor; v.w *= factor;
            xsb[xr + 16 * i][xk] = v;
        }
        float* wsf = (float*)wsh;
#pragma unroll
        for (int j = 0; j < 4; ++j) {
            const int kk = (wk << 4) + (j << 2);
            wsf[(kk + 0) * E + we] = wb[j].x;
            wsf[(kk + 1) * E + we] = wb[j].y;
            wsf[(kk + 2) * E + we] = wb[j].z;
            wsf[(kk + 3) * E + we] = wb[j].w;
        }
        __syncthreads();
        if (t + 1 < 32) {
            const int k0 = (t + 1) * 64;
#pragma unroll
            for (int i = 0; i < 2; ++i)
                xb[i] = *(const float4*)(xg + (xr + 16 * i) * D + k0 + (xk << 2));
#pragma unroll
            for (int j = 0; j < 4; ++j)
                wb[j] = *(const float4*)(W + we * D + k0 + (wk << 4) + (j << 2));
        }
#pragma unroll
        for (int kg = 0; kg < 16; ++kg) {
            float4 xv[2], wv[4];
#pragma unroll
            for (int i = 0; i < 2; ++i) xv[i] = xsb[rg + 16 * i][kg];
#pragma unroll
            for (int c = 0; c < 4; ++c) wv[c] = wsh[(kg << 2) + c][eg];
#pragma unroll
            for (int i = 0; i < 2; ++i) {
                const float x0 = xv[i].x, x1 = xv[i].y, x2 = xv[i].z, x3 = xv[i].w;
                acc[i][0] += x0 * wv[0].x; acc[i][1] += x0 * wv[0].y;
                acc[i][2] += x0 * wv[0].z; acc[i][3] += x0 * wv[0].w;
                acc[i][0] += x1 * wv[1].x; acc[i][1] += x1 * wv[1].y;
                acc[i][2] += x1 * wv[1].z; acc[i][3] += x1 * wv[1].w;
                acc[i][0] += x2 * wv[2].x; acc[i][1] += x2 * wv[2].y;
                acc[i][2] += x2 * wv[2].z; acc[i][3] += x2 * wv[2].w;
                acc[i][0] += x3 * wv[3].x; acc[i][1] += x3 * wv[3].y;
                acc[i][2] += x3 * wv[3].z; acc[i][3] += x3 * wv[3].w;
            }
        }
        __syncthreads();
    }
#pragma unroll
    for (int i = 0; i < 2; ++i) {
        const int gRow = rowBase + rg + 16 * i;
        const float4 nz = *(const float4*)(noise + (size_t)gRow * E + e0);
        float4 o;
        o.x = acc[i][0] + 0.1f * nz.x; o.y = acc[i][1] + 0.1f * nz.y;
        o.z = acc[i][2] + 0.1f * nz.z; o.w = acc[i][3] + 0.1f * nz.w;
        *(float4*)(logits_out + (size_t)gRow * E + e0) = o;
    }
}

__global__ __launch_bounds__(256)
void topk_r2(float* __restrict__ probs, float* __restrict__ dispatch,
             float* __restrict__ sel)
{
    const int lane = threadIdx.x & 63;
    const int wave = threadIdx.x >> 6;
    const int row  = blockIdx.x * 4 + wave;
    const float v = probs[(size_t)row * E + lane];
    float m = v;
#pragma unroll
    for (int off = 32; off > 0; off >>= 1)
        m = fmaxf(m, __shfl_xor(m, off, 64));
    const float p = expf(v - m);
    float s = p;
#pragma unroll
    for (int off = 32; off > 0; off >>= 1)
        s += __shfl_xor(s, off, 64);
    const float prob = p / s;
    probs[(size_t)row * E + lane] = prob;
    float bv = prob; int bi = lane;
#pragma unroll
    for (int off = 32; off > 0; off >>= 1) {
        const float ov = __shfl_xor(bv, off, 64);
        const int   oi = __shfl_xor(bi, off, 64);
        if (ov > bv || (ov == bv && oi < bi)) { bv = ov; bi = oi; }
    }
    float cv = (lane == bi) ? -INFINITY : prob;
    int ci = lane;
#pragma unroll
    for (int off = 32; off > 0; off >>= 1) {
        const float ov = __shfl_xor(cv, off, 64);
        const int   oi = __shfl_xor(ci, off, 64);
        if (ov > cv || (ov == cv && oi < ci)) { cv = ov; ci = oi; }
    }
    const float sum2 = bv + cv;
    float dval = 0.f;
    if (lane == bi) dval = bv / sum2;
    if (lane == ci) dval = cv / sum2;
    dispatch[(size_t)row * E + lane] = dval;
    if (lane == 0) {
        float2 sv; sv.x = (float)bi; sv.y = (float)ci;
        *(float2*)(sel + (size_t)row * 2) = sv;
    }
}

extern "C" void kernel_launch(void* const* d_in, const int* in_sizes, int n_in,
                              void* d_out, int out_size, void* d_ws, size_t ws_size,
                              hipStream_t stream) {
    const float* x     = (const float*)d_in[0];
    const float* W     = (const float*)d_in[1];
    const float* scond = (const float*)d_in[2];
    const float* noise = (const float*)d_in[3];
    const int*   sidx  = (const int*)d_in[4];

    float* out      = (float*)d_out;
    float* dispatch = out;
    float* probs    = out + (size_t)NROWS * E;
    float* sel      = out + 2 * (size_t)NROWS * E;

    if (ws_size >= WCVT_BYTES) {
        unsigned short* whi = (unsigned short*)d_ws;
        unsigned short* wlo = whi + (size_t)E * D;
        w_cvt<<<dim3(64), dim3(256), 0, stream>>>(W, whi, wlo);
        moe_fused<<<dim3(NROWS / ROWS_PB), dim3(256), 0, stream>>>(
            x, whi, wlo, scond, sidx, noise, dispatch, probs, sel);
    } else {
        gemm_r2<<<dim3(NROWS / 32), dim3(256), 0, stream>>>(
            x, W, scond, noise, sidx, probs);
        topk_r2<<<dim3(NROWS / 4), dim3(256), 0, stream>>>(
            probs, dispatch, sel);
    }
}